// Round 4
// baseline (512.685 us; speedup 1.0000x reference)
//
#include <hip/hip_runtime.h>
#include <math.h>

#define EMBED 1024
#define HIDDEN 4096
#define ROWS_CAP 3072

// workspace layout (bytes)
#define WS_COUNT   0
#define WS_BASE    64
#define WS_TIDX    4096
#define WS_TW      12288
#define WS_ROWTOK  20480
#define WS_ROWW    32768
#define WS_XB      65536
#define WS_H       2162688ULL
#define WS_W1R     27328512ULL
#define WS_W2R     94437376ULL
#define WS_NEED    161546240ULL

typedef short short8 __attribute__((ext_vector_type(8)));
typedef float f32x4 __attribute__((ext_vector_type(4)));

typedef const __attribute__((address_space(1))) unsigned int* gas_t;
typedef __attribute__((address_space(3))) unsigned int* las_t;

__device__ __forceinline__ void gl16(const void* g, void* l) {
  __builtin_amdgcn_global_load_lds((gas_t)g, (las_t)l, 16, 0, 0);
}

__device__ __forceinline__ short f2bf(float f) {
  __bf16 h = (__bf16)f;
  return __builtin_bit_cast(short, h);
}

__device__ __forceinline__ short8 pack8(float4 a, float4 b) {
  short8 r;
  r[0] = f2bf(a.x); r[1] = f2bf(a.y); r[2] = f2bf(a.z); r[3] = f2bf(a.w);
  r[4] = f2bf(b.x); r[5] = f2bf(b.y); r[6] = f2bf(b.z); r[7] = f2bf(b.w);
  return r;
}

// ---------------- router (+ x -> bf16 cast fused) ----------------
__global__ __launch_bounds__(256) void router_kernel(
    const float* __restrict__ x, const float* __restrict__ gw,
    int* __restrict__ count, int2* __restrict__ t_idx, float2* __restrict__ t_w,
    unsigned short* __restrict__ xb) {
  int t = blockIdx.x * 4 + (threadIdx.x >> 6);
  int lane = threadIdx.x & 63;
  const float* xr = x + (size_t)t * EMBED;
  unsigned short* xbr = xb + (size_t)t * EMBED;
  float acc[8] = {0.f,0.f,0.f,0.f,0.f,0.f,0.f,0.f};
#pragma unroll
  for (int c = 0; c < 4; ++c) {
    float4 xv = *(const float4*)(xr + lane * 4 + c * 256);
    ushort4 o;
    o.x = (unsigned short)f2bf(xv.x); o.y = (unsigned short)f2bf(xv.y);
    o.z = (unsigned short)f2bf(xv.z); o.w = (unsigned short)f2bf(xv.w);
    *(ushort4*)(xbr + lane * 4 + c * 256) = o;
#pragma unroll
    for (int e = 0; e < 8; ++e) {
      float4 gv = *(const float4*)(gw + e * EMBED + lane * 4 + c * 256);
      acc[e] += xv.x * gv.x + xv.y * gv.y + xv.z * gv.z + xv.w * gv.w;
    }
  }
#pragma unroll
  for (int e = 0; e < 8; ++e) {
#pragma unroll
    for (int off = 32; off > 0; off >>= 1) acc[e] += __shfl_down(acc[e], off);
  }
  if (lane == 0) {
    float m = acc[0];
#pragma unroll
    for (int e = 1; e < 8; ++e) m = fmaxf(m, acc[e]);
    float p[8]; float s = 0.f;
#pragma unroll
    for (int e = 0; e < 8; ++e) { p[e] = expf(acc[e] - m); s += p[e]; }
    float inv = 1.0f / s;
#pragma unroll
    for (int e = 0; e < 8; ++e) p[e] *= inv;
    int i0 = 0; float p0 = p[0];
#pragma unroll
    for (int e = 1; e < 8; ++e) if (p[e] > p0) { p0 = p[e]; i0 = e; }
    int i1 = -1; float p1 = -1.f;
#pragma unroll
    for (int e = 0; e < 8; ++e) if (e != i0 && p[e] > p1) { p1 = p[e]; i1 = e; }
    float denom = p0 + p1 + 1e-9f;
    atomicAdd(&count[i0], 1);
    atomicAdd(&count[i1], 1);
    t_idx[t] = make_int2(i0, i1);
    t_w[t] = make_float2(p0 / denom, p1 / denom);
  }
}

// ---------------- assign ----------------
__global__ __launch_bounds__(256) void assign_kernel(
    const int* __restrict__ count, int* __restrict__ base,
    const int2* __restrict__ t_idx, const float2* __restrict__ t_w,
    int* __restrict__ row_token, float* __restrict__ row_w, int T) {
  __shared__ int s_base[8];
  __shared__ int s_cur[8];
  int tid = threadIdx.x;
  for (int i = tid; i < ROWS_CAP; i += 256) row_token[i] = -1;
  if (tid == 0) {
    int b = 0;
    for (int e = 0; e < 8; ++e) {
      s_base[e] = b; base[e] = b;
      b += (count[e] + 127) & ~127;
    }
  }
  if (tid < 8) s_cur[tid] = 0;
  __syncthreads();
  for (int t = tid; t < T; t += 256) {
    int2 ii = t_idx[t]; float2 ww = t_w[t];
    int p = atomicAdd(&s_cur[ii.x], 1);
    int r = s_base[ii.x] + p;
    row_token[r] = t; row_w[r] = ww.x;
    p = atomicAdd(&s_cur[ii.y], 1);
    r = s_base[ii.y] + p;
    row_token[r] = t; row_w[r] = ww.y;
  }
}

// ---------------- repack weights fp32 [k][n] -> bf16 tiles [e][nt128][kc][n128][k32] ----------------
__global__ __launch_bounds__(256) void repack_w_kernel(
    const float* __restrict__ w1, const float* __restrict__ w2,
    unsigned short* __restrict__ w1r, unsigned short* __restrict__ w2r) {
  __shared__ float tile[32 * 129];
  int b = blockIdx.x;
  const float* src; unsigned short* dst; int N;
  if (b < 8192) {
    int kc = b & 31, nt = (b >> 5) & 31, e = b >> 10;
    N = HIDDEN;
    src = w1 + (size_t)e * EMBED * HIDDEN + (size_t)(kc * 32) * HIDDEN + nt * 128;
    dst = w1r + (size_t)b * 4096;
  } else {
    int b2 = b - 8192;
    int kc = b2 & 127, nt = (b2 >> 7) & 7, e = b2 >> 10;
    N = EMBED;
    src = w2 + (size_t)e * HIDDEN * EMBED + (size_t)(kc * 32) * EMBED + nt * 128;
    dst = w2r + (size_t)b2 * 4096;
  }
  int t = threadIdx.x;
  // batch all 4 loads into registers first (avoid per-load vmcnt serialization)
  float4 v[4];
#pragma unroll
  for (int r = 0; r < 4; ++r) {
    int idx = r * 256 + t;
    v[r] = *(const float4*)(src + (size_t)(idx >> 5) * N + (idx & 31) * 4);
  }
#pragma unroll
  for (int r = 0; r < 4; ++r) {
    int idx = r * 256 + t;
    int k = idx >> 5;
    int n4 = (idx & 31) * 4;
    tile[k * 129 + n4 + 0] = v[r].x;
    tile[k * 129 + n4 + 1] = v[r].y;
    tile[k * 129 + n4 + 2] = v[r].z;
    tile[k * 129 + n4 + 3] = v[r].w;
  }
  __syncthreads();
  int n = t >> 1, half = t & 1;
  short8 o0, o1;
#pragma unroll
  for (int j = 0; j < 8; ++j) o0[j] = f2bf(tile[(half * 16 + j) * 129 + n]);
#pragma unroll
  for (int j = 0; j < 8; ++j) o1[j] = f2bf(tile[(half * 16 + 8 + j) * 129 + n]);
  *(short8*)(dst + n * 32 + half * 16) = o0;
  *(short8*)(dst + n * 32 + half * 16 + 8) = o1;
}

// ---------------- FFN1: H = gelu(Xb @ W1r + b1) ----------------
// BM=128, BN=64, BK=32. grid 4096 (1-D, XCD-swizzled):
//   g = mt*8 + (flat&7) + (flat>>3)*64, flat = e*64+nt  -> all mt of one (e,nt) share g%8 (XCD)
__global__ __launch_bounds__(256) void ffn1_kernel(
    const unsigned short* __restrict__ xb, const unsigned short* __restrict__ w1r,
    const float* __restrict__ b1, const int* __restrict__ count,
    const int* __restrict__ base, const int* __restrict__ row_token,
    unsigned short* __restrict__ H) {
  int g = blockIdx.x;
  int low3 = g & 7;
  int mt = (g >> 3) & 7;
  int flat = (g >> 6) * 8 + low3;   // e*64 + nt
  int e = flat >> 6, nt = flat & 63;
  int cnt = count[e];
  if (mt * 128 >= cnt) return;
  int base_e = base[e];

  __shared__ __align__(16) short As[128 * 32];
  __shared__ __align__(16) short Bs[64 * 32];

  int tid = threadIdx.x, w = tid >> 6, l = tid & 63;
  int lq = l >> 2, lr = l & 3;

  const unsigned short* aptr[2];
#pragma unroll
  for (int c = 0; c < 2; ++c) {
    int r = (w * 2 + c) * 16 + lq;
    int pos = mt * 128 + r;
    int tok = (pos < cnt) ? row_token[base_e + pos] : 0;
    if (tok < 0) tok = 0;
    aptr[c] = xb + (size_t)tok * EMBED + lr * 8;
  }
  const unsigned short* bptr = w1r + ((size_t)(e * 32 + (nt >> 1)) * 32) * 4096
                               + (nt & 1) * 2048 + w * 512 + lq * 32 + lr * 8;
  short* As_st = As + w * 1024;   // chunk c at +c*512 shorts
  short* Bs_st = Bs + w * 512;

  int wm = w & 1, wn = w >> 1;
  int quad = l >> 4, l15 = l & 15;
  const short* Afr = As + (wm * 64 + l15) * 32 + quad * 8;
  const short* Bfr = Bs + (wn * 32 + l15) * 32 + quad * 8;

  f32x4 acc[4][2];
#pragma unroll
  for (int i = 0; i < 4; ++i)
#pragma unroll
    for (int j = 0; j < 2; ++j) acc[i][j] = (f32x4){0.f, 0.f, 0.f, 0.f};

  for (int kc = 0; kc < 32; ++kc) {
    gl16(aptr[0] + kc * 32, As_st);
    gl16(aptr[1] + kc * 32, As_st + 512);
    gl16(bptr + (size_t)kc * 4096, Bs_st);
    __syncthreads();
    short8 a[4], bb[2];
#pragma unroll
    for (int i = 0; i < 4; ++i) a[i]  = *(const short8*)(Afr + i * 16 * 32);
#pragma unroll
    for (int j = 0; j < 2; ++j) bb[j] = *(const short8*)(Bfr + j * 16 * 32);
#pragma unroll
    for (int i = 0; i < 4; ++i)
#pragma unroll
      for (int j = 0; j < 2; ++j)
        acc[i][j] = __builtin_amdgcn_mfma_f32_16x16x32_bf16(a[i], bb[j], acc[i][j], 0, 0, 0);
    __syncthreads();
  }

  const float* b1e = b1 + e * HIDDEN;
#pragma unroll
  for (int i = 0; i < 4; ++i) {
    int rl = wm * 64 + i * 16 + quad * 4;
#pragma unroll
    for (int rg = 0; rg < 4; ++rg) {
      int pos = mt * 128 + rl + rg;
      if (pos < cnt) {
        unsigned short* hrow = H + (size_t)(base_e + pos) * HIDDEN;
#pragma unroll
        for (int j = 0; j < 2; ++j) {
          int col = nt * 64 + wn * 32 + j * 16 + l15;
          float v = acc[i][j][rg] + b1e[col];
          float gl = 0.5f * v * (1.0f + erff(v * 0.70710678118654752f));
          hrow[col] = (unsigned short)f2bf(gl);
        }
      }
    }
  }
}

// ---------------- FFN2: out += w_r * (H @ W2r + b2) ----------------
// BM=256, BN=64, BK=32, split-K=8 (512 each). grid 4096 (1-D, XCD-swizzled):
//   g = nt*8 + sp + (e*4+mt)*128  -> all nt of one (e,mt,sp) share g%8 (XCD, A-tile reuse)
__global__ __launch_bounds__(256) void ffn2_kernel(
    const unsigned short* __restrict__ H, const unsigned short* __restrict__ w2r,
    const float* __restrict__ b2, const int* __restrict__ count,
    const int* __restrict__ base, const int* __restrict__ row_token,
    const float* __restrict__ row_w, float* __restrict__ out) {
  int g = blockIdx.x;
  int sp = g & 7;
  int nt = (g >> 3) & 15;
  int emt = g >> 7;
  int e = emt >> 2, mt = emt & 3;
  int cnt = count[e];
  if (mt * 256 >= cnt) return;
  int base_e = base[e];

  __shared__ __align__(16) short As[256 * 32];
  __shared__ __align__(16) short Bs[64 * 32];

  int tid = threadIdx.x, w = tid >> 6, l = tid & 63;
  int lq = l >> 2, lr = l & 3;

  const unsigned short* aptr[4];
#pragma unroll
  for (int c = 0; c < 4; ++c) {
    int r = (w * 4 + c) * 16 + lq;
    int rowg = base_e + mt * 256 + r;
    if (rowg > ROWS_CAP - 1) rowg = ROWS_CAP - 1;
    aptr[c] = H + (size_t)rowg * HIDDEN + sp * 512 + lr * 8;
  }
  const unsigned short* bptr =
      w2r + ((size_t)(e * 8 + (nt >> 1)) * 128 + sp * 16) * 4096
      + (nt & 1) * 2048 + w * 512 + lq * 32 + lr * 8;
  short* As_st = As + w * 2048;   // chunk c at +c*512 shorts
  short* Bs_st = Bs + w * 512;

  int quad = l >> 4, l15 = l & 15;
  const short* Afr = As + (w * 64 + l15) * 32 + quad * 8;
  const short* Bfr = Bs + l15 * 32 + quad * 8;

  f32x4 acc[4][4];
#pragma unroll
  for (int i = 0; i < 4; ++i)
#pragma unroll
    for (int j = 0; j < 4; ++j) acc[i][j] = (f32x4){0.f, 0.f, 0.f, 0.f};

  for (int kc = 0; kc < 16; ++kc) {
    gl16(aptr[0] + kc * 32, As_st);
    gl16(aptr[1] + kc * 32, As_st + 512);
    gl16(aptr[2] + kc * 32, As_st + 1024);
    gl16(aptr[3] + kc * 32, As_st + 1536);
    gl16(bptr + (size_t)kc * 4096, Bs_st);
    __syncthreads();
    short8 a[4], bb[4];
#pragma unroll
    for (int i = 0; i < 4; ++i) a[i]  = *(const short8*)(Afr + i * 16 * 32);
#pragma unroll
    for (int j = 0; j < 4; ++j) bb[j] = *(const short8*)(Bfr + j * 16 * 32);
#pragma unroll
    for (int i = 0; i < 4; ++i)
#pragma unroll
      for (int j = 0; j < 4; ++j)
        acc[i][j] = __builtin_amdgcn_mfma_f32_16x16x32_bf16(a[i], bb[j], acc[i][j], 0, 0, 0);
    __syncthreads();
  }

  const float* b2e = b2 + e * EMBED;
#pragma unroll
  for (int i = 0; i < 4; ++i) {
    int rl = w * 64 + i * 16 + quad * 4;
#pragma unroll
    for (int rg = 0; rg < 4; ++rg) {
      int pos = mt * 256 + rl + rg;
      if (pos < cnt) {
        int r = base_e + pos;
        int tok = row_token[r];
        float wgt = row_w[r];
        float* orow = out + (size_t)tok * EMBED;
#pragma unroll
        for (int j = 0; j < 4; ++j) {
          int col = nt * 64 + j * 16 + l15;
          float v = acc[i][j][rg] + (sp == 0 ? b2e[col] : 0.f);
          atomicAdd(orow + col, v * wgt);
        }
      }
    }
  }
}

// ================= fallback (R1-proven) used when ws_size too small =================
__global__ __launch_bounds__(256) void ffn1_fb_kernel(
    const float* __restrict__ x, const float* __restrict__ w1,
    const float* __restrict__ b1, const int* __restrict__ count,
    const int* __restrict__ base, const int* __restrict__ row_token,
    unsigned short* __restrict__ H) {
  int nt = blockIdx.x;
  int e  = blockIdx.y >> 3;
  int mt = blockIdx.y & 7;
  int cnt = count[e];
  if (mt * 128 >= cnt) return;
  int base_e = base[e];
  int n0 = nt * 128;
  const float* w1e = w1 + (size_t)e * EMBED * HIDDEN;

  __shared__ __align__(16) short As[128 * 40];
  __shared__ __align__(16) short Bs[128 * 40];

  int tid = threadIdx.x;
  int arow = tid >> 1;
  int akq  = (tid & 1) * 16;
  int a_pos = mt * 128 + arow;
  int a_tok = (a_pos < cnt) ? row_token[base_e + a_pos] : -1;
  const float* a_src = x + (size_t)(a_tok < 0 ? 0 : a_tok) * EMBED + akq;
  short* As_dst = &As[arow * 40 + akq];
  int bn  = tid & 127;
  int bk0 = (tid >> 7) * 16;
  const float* b_src = w1e + (size_t)(n0 + bn);
  short* Bs_dst = &Bs[bn * 40 + bk0];

  int lane = tid & 63, wv = tid >> 6;
  int quad = lane >> 4, l15 = lane & 15;
  const short* Abase = &As[((wv & 1) * 64 + l15) * 40 + quad * 8];
  const short* Bbase = &Bs[((wv >> 1) * 64 + l15) * 40 + quad * 8];

  f32x4 acc[4][4];
#pragma unroll
  for (int i = 0; i < 4; ++i)
#pragma unroll
    for (int j = 0; j < 4; ++j) acc[i][j] = (f32x4){0.f, 0.f, 0.f, 0.f};

  for (int kk = 0; kk < EMBED; kk += 32) {
    short8 av0 = {0,0,0,0,0,0,0,0}, av1 = {0,0,0,0,0,0,0,0};
    if (a_tok >= 0) {
      const float4* p = (const float4*)(a_src + kk);
      av0 = pack8(p[0], p[1]); av1 = pack8(p[2], p[3]);
    }
    float bv[16];
#pragma unroll
    for (int j = 0; j < 16; ++j) bv[j] = b_src[(size_t)(kk + bk0 + j) * HIDDEN];
    short8 blo, bhi;
#pragma unroll
    for (int j = 0; j < 8; ++j) { blo[j] = f2bf(bv[j]); bhi[j] = f2bf(bv[j + 8]); }
    *(short8*)As_dst = av0; *(short8*)(As_dst + 8) = av1;
    *(short8*)Bs_dst = blo; *(short8*)(Bs_dst + 8) = bhi;
    __syncthreads();
    short8 af[4], bfv[4];
#pragma unroll
    for (int i = 0; i < 4; ++i) {
      af[i]  = *(const short8*)(Abase + i * 16 * 40);
      bfv[i] = *(const short8*)(Bbase + i * 16 * 40);
    }
#pragma unroll
    for (int i = 0; i < 4; ++i)
#pragma unroll
      for (int j = 0; j < 4; ++j)
        acc[i][j] = __builtin_amdgcn_mfma_f32_16x16x32_bf16(af[i], bfv[j], acc[i][j], 0, 0, 0);
    __syncthreads();
  }

  const float* b1e = b1 + e * HIDDEN;
#pragma unroll
  for (int i = 0; i < 4; ++i) {
    int rl = (wv & 1) * 64 + i * 16 + quad * 4;
#pragma unroll
    for (int rg = 0; rg < 4; ++rg) {
      int pos = mt * 128 + rl + rg;
      if (pos < cnt) {
        unsigned short* hrow = H + (size_t)(base_e + pos) * HIDDEN;
#pragma unroll
        for (int j = 0; j < 4; ++j) {
          int col = n0 + (wv >> 1) * 64 + j * 16 + l15;
          float v = acc[i][j][rg] + b1e[col];
          float gl = 0.5f * v * (1.0f + erff(v * 0.70710678118654752f));
          hrow[col] = (unsigned short)f2bf(gl);
        }
      }
    }
  }
}

__global__ __launch_bounds__(256) void ffn2_fb_kernel(
    const unsigned short* __restrict__ H, const float* __restrict__ w2,
    const float* __restrict__ b2, const int* __restrict__ count,
    const int* __restrict__ base, const int* __restrict__ row_token,
    const float* __restrict__ row_w, float* __restrict__ out) {
  int nt = blockIdx.x;
  int e  = blockIdx.y >> 3;
  int mt = blockIdx.y & 7;
  int cnt = count[e];
  if (mt * 128 >= cnt) return;
  int base_e = base[e];
  int n0 = nt * 64;
  const float* w2e = w2 + (size_t)e * HIDDEN * EMBED;

  __shared__ __align__(16) short As[128 * 40];
  __shared__ __align__(16) short Bs[64 * 40];

  int tid = threadIdx.x;
  int arow = tid >> 1;
  int akq  = (tid & 1) * 16;
  int a_pos = mt * 128 + arow;
  bool a_ok = (a_pos < cnt);
  const unsigned short* a_src = H + (size_t)(base_e + (a_ok ? a_pos : 0)) * HIDDEN + akq;
  short* As_dst = &As[arow * 40 + akq];
  int bn  = tid & 63;
  int bk0 = (tid >> 6) * 8;
  const float* b_src = w2e + (size_t)(n0 + bn);
  short* Bs_dst = &Bs[bn * 40 + bk0];

  int lane = tid & 63, wv = tid >> 6;
  int quad = lane >> 4, l15 = lane & 15;
  const short* Abase = &As[((wv & 1) * 64 + l15) * 40 + quad * 8];
  const short* Bbase = &Bs[((wv >> 1) * 32 + l15) * 40 + quad * 8];

  f32x4 acc[4][2];
#pragma unroll
  for (int i = 0; i < 4; ++i)
#pragma unroll
    for (int j = 0; j < 2; ++j) acc[i][j] = (f32x4){0.f, 0.f, 0.f, 0.f};

  for (int kk = 0; kk < HIDDEN; kk += 32) {
    short8 av0 = {0,0,0,0,0,0,0,0}, av1 = {0,0,0,0,0,0,0,0};
    if (a_ok) {
      const short8* p = (const short8*)(a_src + kk);
      av0 = p[0]; av1 = p[1];
    }
    float bv[8];
#pragma unroll
    for (int j = 0; j < 8; ++j) bv[j] = b_src[(size_t)(kk + bk0 + j) * EMBED];
    short8 bpk;
#pragma unroll
    for (int j = 0; j < 8; ++j) bpk[j] = f2bf(bv[j]);
    *(short8*)As_dst = av0; *(short8*)(As_dst + 8) = av1;
    *(short8*)Bs_dst = bpk;
    __syncthreads();
    short8 af[4], bf2[2];
#pragma unroll
    for (int i = 0; i < 4; ++i) af[i] = *(const short8*)(Abase + i * 16 * 40);
#pragma unroll
    for (int j = 0; j < 2; ++j) bf2[j] = *(const short8*)(Bbase + j * 16 * 40);
#pragma unroll
    for (int i = 0; i < 4; ++i)
#pragma unroll
      for (int j = 0; j < 2; ++j)
        acc[i][j] = __builtin_amdgcn_mfma_f32_16x16x32_bf16(af[i], bf2[j], acc[i][j], 0, 0, 0);
    __syncthreads();
  }

  const float* b2e = b2 + e * EMBED;
#pragma unroll
  for (int i = 0; i < 4; ++i) {
    int rl = (wv & 1) * 64 + i * 16 + quad * 4;
#pragma unroll
    for (int rg = 0; rg < 4; ++rg) {
      int pos = mt * 128 + rl + rg;
      if (pos < cnt) {
        int r = base_e + pos;
        int tok = row_token[r];
        float wgt = row_w[r];
        float* orow = out + (size_t)tok * EMBED;
#pragma unroll
        for (int j = 0; j < 2; ++j) {
          int col = n0 + (wv >> 1) * 32 + j * 16 + l15;
          float v = acc[i][j][rg] + b2e[col];
          atomicAdd(orow + col, v * wgt);
        }
      }
    }
  }
}

extern "C" void kernel_launch(void* const* d_in, const int* in_sizes, int n_in,
                              void* d_out, int out_size, void* d_ws, size_t ws_size,
                              hipStream_t stream) {
  (void)n_in;
  const float* x   = (const float*)d_in[0];
  const float* gw  = (const float*)d_in[1];
  const float* w1  = (const float*)d_in[2];
  const float* b1  = (const float*)d_in[3];
  const float* w2  = (const float*)d_in[4];
  const float* b2  = (const float*)d_in[5];
  float* out = (float*)d_out;
  int T = in_sizes[0] / EMBED;  // 1024

  char* w = (char*)d_ws;
  int*    count     = (int*)(w + WS_COUNT);
  int*    base      = (int*)(w + WS_BASE);
  int2*   t_idx     = (int2*)(w + WS_TIDX);
  float2* t_w       = (float2*)(w + WS_TW);
  int*    row_token = (int*)(w + WS_ROWTOK);
  float*  row_w     = (float*)(w + WS_ROWW);
  unsigned short* xb  = (unsigned short*)(w + WS_XB);
  unsigned short* H   = (unsigned short*)(w + WS_H);
  unsigned short* w1r = (unsigned short*)(w + WS_W1R);
  unsigned short* w2r = (unsigned short*)(w + WS_W2R);

  hipMemsetAsync(count, 0, 32, stream);
  hipMemsetAsync(out, 0, (size_t)out_size * sizeof(float), stream);

  if (ws_size >= WS_NEED) {
    router_kernel<<<T / 4, 256, 0, stream>>>(x, gw, count, t_idx, t_w, xb);
    assign_kernel<<<1, 256, 0, stream>>>(count, base, t_idx, t_w, row_token, row_w, T);
    repack_w_kernel<<<16384, 256, 0, stream>>>(w1, w2, w1r, w2r);
    ffn1_kernel<<<4096, 256, 0, stream>>>(xb, w1r, b1, count, base, row_token, H);
    ffn2_kernel<<<4096, 256, 0, stream>>>(H, w2r, b2, count, base, row_token, row_w, out);
  } else {
    router_kernel<<<T / 4, 256, 0, stream>>>(x, gw, count, t_idx, t_w, xb);
    assign_kernel<<<1, 256, 0, stream>>>(count, base, t_idx, t_w, row_token, row_w, T);
    ffn1_fb_kernel<<<dim3(HIDDEN / 128, 64), 256, 0, stream>>>(x, w1, b1, count, base, row_token, H);
    ffn2_fb_kernel<<<dim3(EMBED / 64, 64), 256, 0, stream>>>(H, w2, b2, count, base, row_token, row_w, out);
  }
}